// Round 6
// baseline (416.712 us; speedup 1.0000x reference)
//
#include <hip/hip_runtime.h>
#include <math.h>

#define BATCH 16
#define NN 25200
#define NCLS 80
#define K_PRE 1024
#define MAX_DET 300
#define CONF_T 0.4f
#define IOU_T 0.45f
#define TBIAS 0x3E000000u
// key layout (47 bits): t(25) << 22 | (NN-1-n)(15) << 7 | cls(7)
// (t, n) unique => cls in low bits never affects sort order.
#define RROWS 128
#define STHREADS 512
#define NCH 25  // ceil(NN/1024) chunks per fused thread

// ---------------------------------------------------------------------------
// K1: LDS-staged score + first-max argmax -> 47-bit key per anchor.
// ---------------------------------------------------------------------------
__global__ void __launch_bounds__(STHREADS) score_kernel(
    const float* __restrict__ pred, unsigned long long* __restrict__ keys) {
    __shared__ float srow[RROWS * 85];

    const int tile = blockIdx.x, b = blockIdx.y, tid = threadIdx.x;
    const int row0 = tile * RROWS;
    int nrows = NN - row0;
    if (nrows > RROWS) nrows = RROWS;

    const float4* g4 = (const float4*)(pred + ((size_t)b * NN + row0) * 85);
    float4* l4 = (float4*)srow;
    const int nf4 = (nrows * 85) >> 2;  // nrows*85 % 4 == 0 always
    for (int i = tid; i < nf4; i += STHREADS) l4[i] = g4[i];
    __syncthreads();

    const int r = tid >> 2, sub = tid & 3;
    float best = 0.0f;
    int bc = sub * 20;
    float obj = 0.0f;
    if (r < nrows) {
        obj = srow[r * 85 + 4];
        if (obj > CONF_T) {
            const float* cp = &srow[r * 85 + 5 + sub * 20];
#pragma unroll
            for (int i = 0; i < 20; ++i) {
                float v = cp[i] * obj;
                if (v > best) { best = v; bc = sub * 20 + i; }  // first-max
            }
        }
    }
#pragma unroll
    for (int d = 1; d < 4; d <<= 1) {
        float ov = __shfl_xor(best, d);
        int oc = __shfl_xor(bc, d);
        if (ov > best || (ov == best && oc < bc)) { best = ov; bc = oc; }
    }
    if (r < nrows && sub == 0) {
        unsigned t = (obj > CONF_T && best > CONF_T)
                         ? (__float_as_uint(best) - TBIAS) : 0u;
        int n = row0 + r;
        keys[(size_t)b * NN + n] =
            ((unsigned long long)t << 22) |
            ((unsigned long long)(unsigned)(NN - 1 - n) << 7) | (unsigned)bc;
    }
}

// ---------------------------------------------------------------------------
// K2: one block per batch. reg-resident keys -> LDS hist -> shfl suffix-scan
// digit select -> compact -> O(n^2) rank-sort (broadcast LDS reads, 2
// barriers) -> decode boxes -> per-thread per-class greedy NMS (no barriers)
// -> ballot rank -> write 300x89 rows. Zeroes its own output slab.
// ---------------------------------------------------------------------------
__global__ void __launch_bounds__(1024) fused_kernel(
    const unsigned long long* __restrict__ keys, const float* __restrict__ pred,
    const float* __restrict__ conf_logits, const float* __restrict__ logits,
    const float* __restrict__ head, float* __restrict__ out) {
    __shared__ unsigned long long skeys[2048];
    __shared__ unsigned long long sorted[1024];
    __shared__ float4 sbox[1024];
    __shared__ unsigned char scls[1024];
    __shared__ unsigned char skf[1024];
    __shared__ short mlist[NCLS * 64];
    __shared__ unsigned mcnt[NCLS];
    __shared__ unsigned hist[1024];
    __shared__ unsigned sS[1024];
    __shared__ unsigned chunkT[16], chunkE[16];
    __shared__ unsigned wsum[16], wpre[16];
    __shared__ unsigned sel_d0, sel_cnt;

    const int b = blockIdx.x, tid = threadIdx.x;
    const int wave = tid >> 6, lane = tid & 63;
    const unsigned long long* bk = keys + (size_t)b * NN;

    // zero this batch's output slab (harness poisons d_out with 0xAA)
    float* ob = out + (size_t)b * MAX_DET * 89;
    for (int i = tid; i < MAX_DET * 89; i += 1024) ob[i] = 0.0f;

    hist[tid] = 0u;
    sorted[tid] = 0ull;
    skeys[tid] = 0ull;
    skeys[tid + 1024] = 0ull;
    if (tid < NCLS) mcnt[tid] = 0u;
    if (tid == 0) { sel_d0 = 0u; sel_cnt = 0u; }

    // pull all 25200 keys into registers (coalesced 8B loads)
    unsigned long long kr[NCH];
#pragma unroll
    for (int q = 0; q < NCH; ++q) {
        int i = q * 1024 + tid;
        kr[q] = (i < NN) ? bk[i] : 0ull;
    }
    __syncthreads();

    // 10-bit digit histogram from registers
#pragma unroll
    for (int q = 0; q < NCH; ++q) {
        unsigned t = (unsigned)(kr[q] >> 22);
        if (t) atomicAdd(&hist[t >> 15], 1u);
    }
    __syncthreads();

    // suffix-inclusive scan S[d] = #keys with digit >= d, via wave shfl
    unsigned s = hist[tid];
#pragma unroll
    for (int off = 1; off < 64; off <<= 1) {
        unsigned v = __shfl_down(s, off);
        if (lane + off < 64) s += v;
    }
    if (lane == 0) chunkT[wave] = s;
    __syncthreads();
    if (tid < 16) {
        unsigned cs = chunkT[tid];
#pragma unroll
        for (int off = 1; off < 16; off <<= 1) {
            unsigned v = __shfl_down(cs, off);
            if (tid + off < 16) cs += v;
        }
        chunkE[tid] = cs - chunkT[tid];  // suffix-exclusive over chunks
    }
    __syncthreads();
    unsigned S = s + chunkE[wave];
    sS[tid] = S;
    __syncthreads();
    unsigned total = sS[0];
    unsigned K = total < 1024u ? total : 1024u;
    if (total) {
        unsigned gt = (tid < 1023) ? sS[tid + 1] : 0u;
        if (gt < K && K <= S) sel_d0 = (unsigned)tid;  // unique writer
    }
    __syncthreads();
    const unsigned d0 = sel_d0;

    // compact keys with digit >= d0 (~K + one bucket)
#pragma unroll
    for (int q = 0; q < NCH; ++q) {
        unsigned long long key = kr[q];
        unsigned t = (unsigned)(key >> 22);
        if (t && (t >> 15) >= d0) {
            unsigned p = atomicAdd(&sel_cnt, 1u);
            if (p < 2048u) skeys[p] = key;
        }
    }
    __syncthreads();
    unsigned cnt = sel_cnt;
    if (cnt > 2048u) cnt = 2048u;

    // rank-sort: each thread ranks 2 slots against all candidates
    // (broadcast LDS reads; keys unique -> ranks are a bijection)
    unsigned long long k0 = skeys[tid], k1 = skeys[tid + 1024];
    int r0 = 0, r1 = 0;
#pragma unroll 4
    for (unsigned j = 0; j < cnt; ++j) {
        unsigned long long kj = skeys[j];
        r0 += (kj > k0);
        r1 += (kj > k1);
    }
    if ((unsigned)tid < cnt && r0 < 1024) sorted[r0] = k0;
    if ((unsigned)(tid + 1024) < cnt && r1 < 1024) sorted[r1] = k1;
    __syncthreads();

    // decode + gather boxes
    unsigned long long mykey = sorted[tid];
    unsigned t = (unsigned)(mykey >> 22);
    int n = NN - 1 - (int)((mykey >> 7) & 32767u);
    if (t) {
        const float* row = pred + ((size_t)b * NN + n) * 85;
        float x = row[0], y = row[1], w = row[2], h = row[3];
        sbox[tid] = make_float4(x - w * 0.5f, y - h * 0.5f,
                                x + w * 0.5f, y + h * 0.5f);
        scls[tid] = (unsigned char)(mykey & 127u);
        skf[tid] = 1;
    } else {
        scls[tid] = 255;
        skf[tid] = 0;
    }
    __syncthreads();

    // in-class rank (deterministic: count earlier same-class candidates)
    if (t) {
        unsigned char myc = (unsigned char)(mykey & 127u);
        int r = 0;
        for (int j = 0; j < tid; ++j) r += (scls[j] == myc);
        if (r < 64) mlist[(int)myc * 64 + r] = (short)tid;
        atomicAdd(&mcnt[myc], 1u);
    }
    __syncthreads();

    // per-class greedy NMS: one thread per class, alive mask in registers
    if (tid < NCLS) {
        int m = (int)mcnt[tid];
        if (m > 64) m = 64;
        unsigned long long alive =
            (m >= 64) ? ~0ull : ((1ull << m) - 1ull);
        const short* ml = &mlist[tid * 64];
        for (int i = 0; i < m - 1; ++i) {
            if (!((alive >> i) & 1ull)) continue;
            float4 bi = sbox[ml[i]];
            float ai = (bi.z - bi.x) * (bi.w - bi.y);
            for (int j = i + 1; j < m; ++j) {
                if (!((alive >> j) & 1ull)) continue;
                float4 bj = sbox[ml[j]];
                float lx = fmaxf(bi.x, bj.x), ly = fmaxf(bi.y, bj.y);
                float rx = fminf(bi.z, bj.z), ry = fminf(bi.w, bj.w);
                float iw = fmaxf(rx - lx, 0.0f), ih = fmaxf(ry - ly, 0.0f);
                float inter = iw * ih;
                float aj = (bj.z - bj.x) * (bj.w - bj.y);
                float iou = inter / (ai + aj - inter + 1e-7f);
                if (iou > IOU_T) alive &= ~(1ull << j);
            }
        }
        for (int i = 0; i < m; ++i)
            if (!((alive >> i) & 1ull)) skf[ml[i]] = 0;
    }
    __syncthreads();

    // output rank via wave ballots (kept rows stay in sorted order)
    int kp = skf[tid];
    unsigned long long bal = __ballot(kp != 0);
    int within = __popcll(bal & ((1ull << lane) - 1ull));
    if (lane == 0) wsum[wave] = (unsigned)__popcll(bal);
    __syncthreads();
    if (tid < 16) {
        unsigned v = wsum[tid], inc = v;
#pragma unroll
        for (int off = 1; off < 16; off <<= 1) {
            unsigned u = __shfl_up(inc, off);
            if (tid >= off) inc += u;
        }
        wpre[tid] = inc - v;  // exclusive prefix
    }
    __syncthreads();
    int rank = (int)wpre[wave] + within;

    if (kp && rank < MAX_DET) {
        float4 bb = sbox[tid];
        float* orow = ob + (size_t)rank * 89;
        orow[0] = bb.x; orow[1] = bb.y; orow[2] = bb.z; orow[3] = bb.w;
        orow[4] = __uint_as_float(t + TBIAS);  // bit-exact top_s
        orow[5] = (float)(int)(mykey & 127u);
        float cl = conf_logits[((size_t)b * NN + n) * 5 + 4];
        float obj_sig = 1.0f / (1.0f + expf(-cl));
        const float4* lrow4 =
            (const float4*)(logits + ((size_t)b * NN + n) * NCLS);
#pragma unroll 4
        for (int q = 0; q < 20; ++q) {
            float4 l4 = lrow4[q];
            orow[6 + 4 * q + 0] = (1.0f / (1.0f + expf(-l4.x))) * obj_sig;
            orow[6 + 4 * q + 1] = (1.0f / (1.0f + expf(-l4.y))) * obj_sig;
            orow[6 + 4 * q + 2] = (1.0f / (1.0f + expf(-l4.z))) * obj_sig;
            orow[6 + 4 * q + 3] = (1.0f / (1.0f + expf(-l4.w))) * obj_sig;
        }
        orow[86] = obj_sig;
        orow[87] = head[(size_t)b * NN + n];
        orow[88] = 1.0f;
    }
}

extern "C" void kernel_launch(void* const* d_in, const int* in_sizes, int n_in,
                              void* d_out, int out_size, void* d_ws,
                              size_t ws_size, hipStream_t stream) {
    const float* pred        = (const float*)d_in[0];
    const float* conf_logits = (const float*)d_in[1];
    const float* logits      = (const float*)d_in[2];
    const float* head        = (const float*)d_in[3];
    float* out = (float*)d_out;

    unsigned long long* keys = (unsigned long long*)d_ws;  // 16*25200*8 B

    dim3 sgrid((NN + RROWS - 1) / RROWS, BATCH);
    score_kernel<<<sgrid, STHREADS, 0, stream>>>(pred, keys);
    fused_kernel<<<BATCH, 1024, 0, stream>>>(keys, pred, conf_logits, logits,
                                             head, out);
}